// Round 7
// baseline (358.354 us; speedup 1.0000x reference)
//
#include <hip/hip_runtime.h>
#include <hip/hip_bf16.h>
#include <stdint.h>

// Problem constants (B=4096, D=2048, K=8, H2=64)
#define NB 4096
#define ND 2048
#define NK 8
#define NH 64

// GEMM tile: 128x128, BK=64, 16x16x32 bf16 MFMA, 512 threads (8 waves, 2Mx4N)
#define BM 128
#define BN 128
#define BK 64
#define MAX_ROWS 5120   // 4096 + padding worst case
#define MAX_TILES 40

// mega-prep grid partition: block 0 = serial small-prep (self-contained),
// then 16384 W1-conv rows, then 4096 x-conv rows.
#define XCONV_FIRST (1 + NK * ND)
#define PREP_GRID   (1 + NK * ND + NB)

typedef __bf16 bf16;
typedef __bf16 bf16x8 __attribute__((ext_vector_type(8)));
typedef float floatx4 __attribute__((ext_vector_type(4)));

// Workspace layout (bytes)
#define OFF_ORDER  0u          // 5120 int (unwritten slots stay poisoned -> negative)
#define OFF_META   20480u      // 81 ints: [0]=n_mt, [1..40]=branch, [41..80]=row0
#define OFF_XC     65536u      // 4096*2048 bf16 = 16777216 B
#define OFF_WB     16842752u   // 8*2048*2048 bf16 = 67108864 B -> end 83951616

__device__ inline void cvt_row16(const float* __restrict__ src, bf16* __restrict__ dst) {
    float4 a = *(const float4*)(src);
    float4 c = *(const float4*)(src + 4);
    bf16x8 v;
    v[0] = (bf16)a.x; v[1] = (bf16)a.y; v[2] = (bf16)a.z; v[3] = (bf16)a.w;
    v[4] = (bf16)c.x; v[5] = (bf16)c.y; v[6] = (bf16)c.z; v[7] = (bf16)c.w;
    *(bf16x8*)dst = v;
}

// ---------------------------------------------------------------------------
// Dispatch 1: block 0 does the whole small-prep chain alone (kidx, counts,
// c2s, meta, scatter, out init) — hidden under 20480 conversion blocks that
// run concurrently (W1 -> branch-split bf16 Wb; x -> bf16 xc in-order).
// ---------------------------------------------------------------------------
__global__ void __launch_bounds__(256)
mega_prep_kernel(const float* __restrict__ x,
                 const float* __restrict__ intention,
                 const float* __restrict__ W1,
                 const float* __restrict__ W2,
                 const float* __restrict__ b2,
                 const float* __restrict__ W3,
                 const float* __restrict__ b3,
                 int* __restrict__ order,
                 int* __restrict__ meta,
                 bf16* __restrict__ xc,
                 bf16* __restrict__ Wb,
                 float* __restrict__ out)
{
    const int blk = blockIdx.x;
    const int tid = threadIdx.x;

    if (blk == 0) {
        // ---- self-contained small prep (one block, ~hidden) ----
        __shared__ int kk_s[NB];      // 16 KB
        __shared__ int cnt[NK];
        __shared__ int cur[NK];
        __shared__ float c2l[NK];

        if (tid < NK) cnt[tid] = 0;
        __syncthreads();

        for (int b = tid; b < NB; b += 256) {
            float4 a = *(const float4*)(intention + (size_t)b * NK);
            float4 c = *(const float4*)(intention + (size_t)b * NK + 4);
            int k = 0;
            if (a.y > 0.5f) k = 1;
            if (a.z > 0.5f) k = 2;
            if (a.w > 0.5f) k = 3;
            if (c.x > 0.5f) k = 4;
            if (c.y > 0.5f) k = 5;
            if (c.z > 0.5f) k = 6;
            if (c.w > 0.5f) k = 7;
            kk_s[b] = k;
            atomicAdd(&cnt[k], 1);
        }
        __syncthreads();

        if (tid < 64) {
            // c2s[k] = b3 + sum_h relu(W2[h,k]+b2[h]) * W3[D+h]  (wave 0)
            const int k = tid & 7;
            const int hc = tid >> 3;
            float s = 0.f;
#pragma unroll
            for (int j = 0; j < 8; j++) {
                int h = hc * 8 + j;
                float v = W2[h * NK + k] + b2[h];
                if (v > 0.f) s += v * W3[ND + h];
            }
            s += __shfl_xor(s, 8, 64);
            s += __shfl_xor(s, 16, 64);
            s += __shfl_xor(s, 32, 64);
            if (tid < 8) c2l[k] = s + b3[0];
        }
        if (tid == 128) {
            // serial M-tile table (other threads idle-cheap)
            int running = 0, nt = 0;
            int c[NK];
#pragma unroll
            for (int k = 0; k < NK; k++) c[k] = cnt[k];
            for (int k = 0; k < NK; k++) {
                cur[k] = running;
                int ntile = (c[k] + BM - 1) / BM;
                for (int t = 0; t < ntile && nt < MAX_TILES; t++) {
                    meta[1 + nt] = k;
                    meta[1 + MAX_TILES + nt] = running + t * BM;
                    nt++;
                }
                running += ntile * BM;
            }
            meta[0] = nt;
        }
        __syncthreads();

        for (int b = tid; b < NB; b += 256) {
            int k = kk_s[b];
            out[b] = c2l[k];
            int pos = atomicAdd(&cur[k], 1);
            if (pos >= 0 && pos < MAX_ROWS) order[pos] = b;
        }
    } else if (blk < XCONV_FIRST) {
        // one W1 row (d*8+k) -> Wb[k][d][:]
        const int r = blk - 1;
        const int d = r >> 3;
        const int k = r & 7;
        cvt_row16(W1 + (size_t)r * ND + tid * 8,
                  Wb + ((size_t)k * ND + d) * ND + tid * 8);
    } else {
        const int row = blk - XCONV_FIRST;
        cvt_row16(x + (size_t)row * ND + tid * 8,
                  xc + (size_t)row * ND + tid * 8);
    }
}

// ---------------------------------------------------------------------------
// Dispatch 2: per-branch bf16 GEMM + fused epilogue.
// 512 threads = 8 waves, 2(M)x4(N); wave tile 64x32 (acc[4][2]).
// BK=64: As/Bs 16 KB each; staging via global_load_lds width-16, each DMA
// instr covers 8 rows x 128 B (lane -> row lane>>3, col (lane&7)*16B, LDS
// byte off = lane*16 from wave-uniform base). A rows gathered via rowb[].
// Epilogue: +b1, relu, *W3, 16-lane shuffle reduce, atomicAdd into out.
// ---------------------------------------------------------------------------
__global__ void __launch_bounds__(512, 4)
gemm_kernel(const bf16* __restrict__ xc,
            const bf16* __restrict__ Wb,
            const int* __restrict__ order,
            const int* __restrict__ meta,
            const float* __restrict__ b1,
            const float* __restrict__ W3,
            float* __restrict__ out)
{
    int n_mt = meta[0];
    if (n_mt > MAX_TILES) n_mt = MAX_TILES;
    const int mt = blockIdx.y;
    if (mt >= n_mt) return;
    const int kbr = meta[1 + mt] & 7;
    int row0 = meta[1 + MAX_TILES + mt];
    if (row0 < 0) row0 = 0;
    if (row0 > MAX_ROWS - BM) row0 = MAX_ROWS - BM;
    const int col0 = blockIdx.x * BN;

    __shared__ bf16 As[BM * BK];   // 16 KB row-major [128][64]
    __shared__ bf16 Bs[BN * BK];   // 16 KB
    __shared__ int rowb[BM];

    const int tid = threadIdx.x;
    const int lane = tid & 63;
    const int w = tid >> 6;        // 0..7
    const int wm = w & 1;          // M half
    const int wn = w >> 1;         // N quarter 0..3

    if (tid < BM) {
        int b = order[row0 + tid];
        rowb[tid] = (b >= 0 && b < NB) ? b : -1;
    }
    __syncthreads();

    // staging rows for this thread: sr0 and sr0+8 (two DMA instrs per buffer)
    const int sr0 = w * 16 + (lane >> 3);
    const int sc = (lane & 7) * 8;            // element offset within row
    const int ra0 = rowb[sr0];
    const int ra1 = rowb[sr0 + 8];
    const bf16* pa0 = xc + (size_t)(ra0 < 0 ? 0 : ra0) * ND + sc;
    const bf16* pa1 = xc + (size_t)(ra1 < 0 ? 0 : ra1) * ND + sc;
    const bf16* pb0 = Wb + ((size_t)kbr * ND + col0 + sr0) * ND + sc;
    const bf16* pb1 = pb0 + (size_t)8 * ND;
    bf16* la0 = As + w * 1024;                // wave-uniform LDS bases (elems)
    bf16* la1 = As + w * 1024 + 512;
    bf16* lb0 = Bs + w * 1024;
    bf16* lb1 = Bs + w * 1024 + 512;

    floatx4 zero = {0.f, 0.f, 0.f, 0.f};
    floatx4 acc[4][2];
#pragma unroll
    for (int i = 0; i < 4; i++)
#pragma unroll
        for (int j = 0; j < 2; j++) acc[i][j] = zero;

    const int qk = (lane >> 4) * 8;
    const int mrow = lane & 15;

    for (int kk = 0; kk < ND; kk += BK) {
        __builtin_amdgcn_global_load_lds(
            (const __attribute__((address_space(1))) void*)(pa0 + kk),
            (__attribute__((address_space(3))) void*)la0, 16, 0, 0);
        __builtin_amdgcn_global_load_lds(
            (const __attribute__((address_space(1))) void*)(pa1 + kk),
            (__attribute__((address_space(3))) void*)la1, 16, 0, 0);
        __builtin_amdgcn_global_load_lds(
            (const __attribute__((address_space(1))) void*)(pb0 + kk),
            (__attribute__((address_space(3))) void*)lb0, 16, 0, 0);
        __builtin_amdgcn_global_load_lds(
            (const __attribute__((address_space(1))) void*)(pb1 + kk),
            (__attribute__((address_space(3))) void*)lb1, 16, 0, 0);
        __syncthreads();

        bf16x8 af[4][2], bfv[2][2];
#pragma unroll
        for (int i = 0; i < 4; i++)
#pragma unroll
            for (int t = 0; t < 2; t++)
                af[i][t] = *(const bf16x8*)(As + (wm * 64 + i * 16 + mrow) * BK + t * 32 + qk);
#pragma unroll
        for (int j = 0; j < 2; j++)
#pragma unroll
            for (int t = 0; t < 2; t++)
                bfv[j][t] = *(const bf16x8*)(Bs + (wn * 32 + j * 16 + mrow) * BK + t * 32 + qk);
#pragma unroll
        for (int t = 0; t < 2; t++)
#pragma unroll
            for (int i = 0; i < 4; i++)
#pragma unroll
                for (int j = 0; j < 2; j++)
                    acc[i][j] = __builtin_amdgcn_mfma_f32_16x16x32_bf16(
                        af[i][t], bfv[j][t], acc[i][j], 0, 0, 0);
        __syncthreads();
    }

    // Epilogue. C/D layout: col = lane&15, row = (lane>>4)*4 + reg.
    const int colq = lane & 15;
    const int quad = lane >> 4;
    float bias[2], w3v[2];
#pragma unroll
    for (int j = 0; j < 2; j++) {
        int d = col0 + wn * 32 + j * 16 + colq;
        bias[j] = b1[d * NK + kbr];
        w3v[j] = W3[d];
    }
#pragma unroll
    for (int i = 0; i < 4; i++) {
#pragma unroll
        for (int r = 0; r < 4; r++) {
            float s = 0.f;
#pragma unroll
            for (int j = 0; j < 2; j++) {
                float v = acc[i][j][r] + bias[j];
                s += (v > 0.f) ? v * w3v[j] : 0.f;
            }
#pragma unroll
            for (int m = 1; m < 16; m <<= 1) s += __shfl_xor(s, m, 64);
            if (colq == 0) {
                int b = rowb[wm * 64 + i * 16 + quad * 4 + r];
                if (b >= 0) atomicAdd(out + b, s);
            }
        }
    }
}

// ---------------------------------------------------------------------------
extern "C" void kernel_launch(void* const* d_in, const int* in_sizes, int n_in,
                              void* d_out, int out_size, void* d_ws, size_t ws_size,
                              hipStream_t stream)
{
    const float* x         = (const float*)d_in[0];
    const float* intention = (const float*)d_in[1];
    const float* W1        = (const float*)d_in[2];
    const float* b1        = (const float*)d_in[3];
    const float* W2        = (const float*)d_in[4];
    const float* b2        = (const float*)d_in[5];
    const float* W3        = (const float*)d_in[6];
    const float* b3        = (const float*)d_in[7];
    float* out = (float*)d_out;

    char* ws = (char*)d_ws;
    int*   order = (int*)(ws + OFF_ORDER);
    int*   meta  = (int*)(ws + OFF_META);
    bf16*  xc    = (bf16*)(ws + OFF_XC);
    bf16*  Wb    = (bf16*)(ws + OFF_WB);

    mega_prep_kernel<<<dim3(PREP_GRID), dim3(256), 0, stream>>>(
        x, intention, W1, W2, b2, W3, b3, order, meta, xc, Wb, out);
    gemm_kernel<<<dim3(ND / BN, MAX_TILES), dim3(512), 0, stream>>>(
        xc, Wb, order, meta, b1, W3, out);
}

// Round 8
// 331.583 us; speedup vs baseline: 1.0807x; 1.0807x over previous
//
#include <hip/hip_runtime.h>
#include <hip/hip_bf16.h>
#include <stdint.h>

// Problem constants (B=4096, D=2048, K=8, H2=64)
#define NB 4096
#define ND 2048
#define NK 8
#define NH 64

// GEMM tile: 128x64, BK=32, 16x16x32 bf16 MFMA, 256 threads (4 waves, 2x2)
// BN=64 doubles the grid (1056 active blocks) to lift grid-bound occupancy.
#define BM 128
#define BN 64
#define BK 32
#define MAX_ROWS 5120   // 4096 + padding worst case
#define MAX_TILES 40

// mega-prep grid partition: block 0 = serial small-prep (self-contained),
// then 16384 W1-conv rows, then 4096 x-conv rows.
#define XCONV_FIRST (1 + NK * ND)
#define PREP_GRID   (1 + NK * ND + NB)

typedef __bf16 bf16;
typedef __bf16 bf16x8 __attribute__((ext_vector_type(8)));
typedef float floatx4 __attribute__((ext_vector_type(4)));

// Workspace layout (bytes)
#define OFF_ORDER  0u          // 5120 int (unwritten slots stay poisoned -> negative)
#define OFF_META   20480u      // 81 ints: [0]=n_mt, [1..40]=branch, [41..80]=row0
#define OFF_XC     65536u      // 4096*2048 bf16 = 16777216 B
#define OFF_WB     16842752u   // 8*2048*2048 bf16 = 67108864 B -> end 83951616

__device__ inline void cvt_row16(const float* __restrict__ src, bf16* __restrict__ dst) {
    float4 a = *(const float4*)(src);
    float4 c = *(const float4*)(src + 4);
    bf16x8 v;
    v[0] = (bf16)a.x; v[1] = (bf16)a.y; v[2] = (bf16)a.z; v[3] = (bf16)a.w;
    v[4] = (bf16)c.x; v[5] = (bf16)c.y; v[6] = (bf16)c.z; v[7] = (bf16)c.w;
    *(bf16x8*)dst = v;
}

// ---------------------------------------------------------------------------
// Dispatch 1: block 0 does the whole small-prep chain alone (kidx, counts,
// c2s, meta, scatter, out init) — hidden under 20480 conversion blocks that
// run concurrently (W1 -> branch-split bf16 Wb; x -> bf16 xc in-order).
// ---------------------------------------------------------------------------
__global__ void __launch_bounds__(256)
mega_prep_kernel(const float* __restrict__ x,
                 const float* __restrict__ intention,
                 const float* __restrict__ W1,
                 const float* __restrict__ W2,
                 const float* __restrict__ b2,
                 const float* __restrict__ W3,
                 const float* __restrict__ b3,
                 int* __restrict__ order,
                 int* __restrict__ meta,
                 bf16* __restrict__ xc,
                 bf16* __restrict__ Wb,
                 float* __restrict__ out)
{
    const int blk = blockIdx.x;
    const int tid = threadIdx.x;

    if (blk == 0) {
        // ---- self-contained small prep (one block, hidden under conv) ----
        __shared__ int kk_s[NB];      // 16 KB
        __shared__ int cnt[NK];
        __shared__ int cur[NK];
        __shared__ float c2l[NK];

        if (tid < NK) cnt[tid] = 0;
        __syncthreads();

        for (int b = tid; b < NB; b += 256) {
            float4 a = *(const float4*)(intention + (size_t)b * NK);
            float4 c = *(const float4*)(intention + (size_t)b * NK + 4);
            int k = 0;
            if (a.y > 0.5f) k = 1;
            if (a.z > 0.5f) k = 2;
            if (a.w > 0.5f) k = 3;
            if (c.x > 0.5f) k = 4;
            if (c.y > 0.5f) k = 5;
            if (c.z > 0.5f) k = 6;
            if (c.w > 0.5f) k = 7;
            kk_s[b] = k;
            atomicAdd(&cnt[k], 1);
        }
        __syncthreads();

        if (tid < 64) {
            // c2s[k] = b3 + sum_h relu(W2[h,k]+b2[h]) * W3[D+h]  (wave 0)
            const int k = tid & 7;
            const int hc = tid >> 3;
            float s = 0.f;
#pragma unroll
            for (int j = 0; j < 8; j++) {
                int h = hc * 8 + j;
                float v = W2[h * NK + k] + b2[h];
                if (v > 0.f) s += v * W3[ND + h];
            }
            s += __shfl_xor(s, 8, 64);
            s += __shfl_xor(s, 16, 64);
            s += __shfl_xor(s, 32, 64);
            if (tid < 8) c2l[k] = s + b3[0];
        }
        if (tid == 128) {
            // serial M-tile table
            int running = 0, nt = 0;
            int c[NK];
#pragma unroll
            for (int k = 0; k < NK; k++) c[k] = cnt[k];
            for (int k = 0; k < NK; k++) {
                cur[k] = running;
                int ntile = (c[k] + BM - 1) / BM;
                for (int t = 0; t < ntile && nt < MAX_TILES; t++) {
                    meta[1 + nt] = k;
                    meta[1 + MAX_TILES + nt] = running + t * BM;
                    nt++;
                }
                running += ntile * BM;
            }
            meta[0] = nt;
        }
        __syncthreads();

        for (int b = tid; b < NB; b += 256) {
            int k = kk_s[b];
            out[b] = c2l[k];
            int pos = atomicAdd(&cur[k], 1);
            if (pos >= 0 && pos < MAX_ROWS) order[pos] = b;
        }
    } else if (blk < XCONV_FIRST) {
        // one W1 row (d*8+k) -> Wb[k][d][:]
        const int r = blk - 1;
        const int d = r >> 3;
        const int k = r & 7;
        cvt_row16(W1 + (size_t)r * ND + tid * 8,
                  Wb + ((size_t)k * ND + d) * ND + tid * 8);
    } else {
        const int row = blk - XCONV_FIRST;
        cvt_row16(x + (size_t)row * ND + tid * 8,
                  xc + (size_t)row * ND + tid * 8);
    }
}

// ---------------------------------------------------------------------------
// Dispatch 2: per-branch bf16 GEMM + fused epilogue (R6 body, BN=64).
// 256 threads = 4 waves (wm,wn in {0,1}); wave tile 64(M)x32(N): acc[4][2].
// Row-major LDS, BK=32 (64B rows — known-good conflict level). Staging via
// global_load_lds width-16: wave w stages rows w*16..w*16+15 of each
// 64-row panel (A needs 2 panels, B needs 1). A rows gathered via rowb[].
// Epilogue: +b1, relu, *W3, 16-lane shuffle reduce, atomicAdd into out.
// ---------------------------------------------------------------------------
__global__ void __launch_bounds__(256)
gemm_kernel(const bf16* __restrict__ xc,
            const bf16* __restrict__ Wb,
            const int* __restrict__ order,
            const int* __restrict__ meta,
            const float* __restrict__ b1,
            const float* __restrict__ W3,
            float* __restrict__ out)
{
    int n_mt = meta[0];
    if (n_mt > MAX_TILES) n_mt = MAX_TILES;
    const int mt = blockIdx.y;
    if (mt >= n_mt) return;
    const int kbr = meta[1 + mt] & 7;
    int row0 = meta[1 + MAX_TILES + mt];
    if (row0 < 0) row0 = 0;
    if (row0 > MAX_ROWS - BM) row0 = MAX_ROWS - BM;
    const int col0 = blockIdx.x * BN;

    __shared__ bf16 As[BM * BK];   // 8 KB row-major [128][32]
    __shared__ bf16 Bs[BN * BK];   // 4 KB row-major [64][32]
    __shared__ int rowb[BM];

    const int tid = threadIdx.x;
    const int lane = tid & 63;
    const int wid = tid >> 6;
    const int wm = wid >> 1;
    const int wn = wid & 1;

    if (tid < BM) {
        int b = order[row0 + tid];
        rowb[tid] = (b >= 0 && b < NB) ? b : -1;
    }
    __syncthreads();

    const int srow = tid >> 2;            // 0..63
    const int scol = (tid & 3) * 8;
    const int ra0 = rowb[srow];
    const int ra1 = rowb[64 + srow];
    const bf16* pa0 = xc + (size_t)(ra0 < 0 ? 0 : ra0) * ND + scol;
    const bf16* pa1 = xc + (size_t)(ra1 < 0 ? 0 : ra1) * ND + scol;
    const bf16* pb0 = Wb + ((size_t)kbr * ND + col0 + srow) * ND + scol;
    bf16* la0 = As + wid * 512;           // wave-uniform LDS bases (elements)
    bf16* la1 = As + 2048 + wid * 512;
    bf16* lb0 = Bs + wid * 512;

    floatx4 zero = {0.f, 0.f, 0.f, 0.f};
    floatx4 acc[4][2];
#pragma unroll
    for (int i = 0; i < 4; i++)
#pragma unroll
        for (int j = 0; j < 2; j++) acc[i][j] = zero;

    const int qk = (lane >> 4) * 8;
    const int mrow = lane & 15;

    for (int kk = 0; kk < ND; kk += BK) {
        __builtin_amdgcn_global_load_lds(
            (const __attribute__((address_space(1))) void*)(pa0 + kk),
            (__attribute__((address_space(3))) void*)la0, 16, 0, 0);
        __builtin_amdgcn_global_load_lds(
            (const __attribute__((address_space(1))) void*)(pa1 + kk),
            (__attribute__((address_space(3))) void*)la1, 16, 0, 0);
        __builtin_amdgcn_global_load_lds(
            (const __attribute__((address_space(1))) void*)(pb0 + kk),
            (__attribute__((address_space(3))) void*)lb0, 16, 0, 0);
        __syncthreads();

        bf16x8 af[4], bfv[2];
#pragma unroll
        for (int i = 0; i < 4; i++)
            af[i] = *(const bf16x8*)(As + (wm * 64 + i * 16 + mrow) * BK + qk);
#pragma unroll
        for (int j = 0; j < 2; j++)
            bfv[j] = *(const bf16x8*)(Bs + (wn * 32 + j * 16 + mrow) * BK + qk);
#pragma unroll
        for (int i = 0; i < 4; i++)
#pragma unroll
            for (int j = 0; j < 2; j++)
                acc[i][j] = __builtin_amdgcn_mfma_f32_16x16x32_bf16(
                    af[i], bfv[j], acc[i][j], 0, 0, 0);
        __syncthreads();
    }

    // Epilogue. C/D layout: col = lane&15, row = (lane>>4)*4 + reg.
    const int colq = lane & 15;
    const int quad = lane >> 4;
    float bias[2], w3v[2];
#pragma unroll
    for (int j = 0; j < 2; j++) {
        int d = col0 + wn * 32 + j * 16 + colq;
        bias[j] = b1[d * NK + kbr];
        w3v[j] = W3[d];
    }
#pragma unroll
    for (int i = 0; i < 4; i++) {
#pragma unroll
        for (int r = 0; r < 4; r++) {
            float s = 0.f;
#pragma unroll
            for (int j = 0; j < 2; j++) {
                float v = acc[i][j][r] + bias[j];
                s += (v > 0.f) ? v * w3v[j] : 0.f;
            }
#pragma unroll
            for (int m = 1; m < 16; m <<= 1) s += __shfl_xor(s, m, 64);
            if (colq == 0) {
                int b = rowb[wm * 64 + i * 16 + quad * 4 + r];
                if (b >= 0) atomicAdd(out + b, s);
            }
        }
    }
}

// ---------------------------------------------------------------------------
extern "C" void kernel_launch(void* const* d_in, const int* in_sizes, int n_in,
                              void* d_out, int out_size, void* d_ws, size_t ws_size,
                              hipStream_t stream)
{
    const float* x         = (const float*)d_in[0];
    const float* intention = (const float*)d_in[1];
    const float* W1        = (const float*)d_in[2];
    const float* b1        = (const float*)d_in[3];
    const float* W2        = (const float*)d_in[4];
    const float* b2        = (const float*)d_in[5];
    const float* W3        = (const float*)d_in[6];
    const float* b3        = (const float*)d_in[7];
    float* out = (float*)d_out;

    char* ws = (char*)d_ws;
    int*   order = (int*)(ws + OFF_ORDER);
    int*   meta  = (int*)(ws + OFF_META);
    bf16*  xc    = (bf16*)(ws + OFF_XC);
    bf16*  Wb    = (bf16*)(ws + OFF_WB);

    mega_prep_kernel<<<dim3(PREP_GRID), dim3(256), 0, stream>>>(
        x, intention, W1, W2, b2, W3, b3, order, meta, xc, Wb, out);
    gemm_kernel<<<dim3(ND / BN, MAX_TILES), dim3(256), 0, stream>>>(
        xc, Wb, order, meta, b1, W3, out);
}